// Round 18
// baseline (299.401 us; speedup 1.0000x reference)
//
#include <hip/hip_runtime.h>
#include <hip/hip_bf16.h>
#include <cstdint>

#define E_ 32
#define H_ 1024
#define I_ 512
#define G_ 8
#define NSH_ 2
#define SCALE_ 2.5f
#define NROUTED (E_ * I_)            // 16384
#define PADCAP (16384 + E_ * 128)    // 20480, pad-to-128

typedef unsigned short u16;
using bf16x8_t = __attribute__((ext_vector_type(8))) __bf16;
using f32x4_t  = __attribute__((ext_vector_type(4))) float;

__device__ __forceinline__ u16 f2bf(float x) {
  union { float f; uint32_t u; } v; v.f = x;
  uint32_t u = v.u;
  uint32_t r = (u + 0x7fffu + ((u >> 16) & 1u)) >> 16;
  return (u16)r;
}
__device__ __forceinline__ float bf2f(u16 x) {
  union { uint32_t u; float f; } v; v.u = ((uint32_t)x) << 16; return v.f;
}

__device__ __forceinline__ void load_lds16(const void* g, void* l) {
  __builtin_amdgcn_global_load_lds(
      (const __attribute__((address_space(1))) unsigned int*)g,
      (__attribute__((address_space(3))) unsigned int*)l,
      16, 0, 0);
}

// u16-element offsets inside wbf: [bg | bu | bd | bshg | bshu | bshd]
#define OFF_BU   16777216L
#define OFF_BD   33554432L
#define OFF_BSHG 50331648L
#define OFF_BSHU 51380224L
#define OFF_BSHD 52428800L
#define WBF_TOT  53477376L

#define W4_WG  4194304L
#define W4_WU  8388608L
#define W4_WD  12582912L
#define W4_SHG 12845056L
#define W4_SHU 13107200L
#define W4_TOT 13369344L

// ---------------- prep: init + gw transpose + all-weight f32->bf16 ----------
__global__ void prep_kernel(const float* __restrict__ gw, float* __restrict__ gwT,
                            int* __restrict__ counts, int* __restrict__ cursor,
                            int* __restrict__ qheads,
                            int* __restrict__ tok_list, float* __restrict__ wt_list,
                            const float* __restrict__ wg, const float* __restrict__ wu,
                            const float* __restrict__ wd, const float* __restrict__ shg,
                            const float* __restrict__ shu, const float* __restrict__ shd,
                            u16* __restrict__ wbf) {
  long i0 = (long)blockIdx.x * blockDim.x + threadIdx.x;
  if (i0 < H_ * E_) {
    int k = (int)(i0 >> 5), e = (int)(i0 & 31);
    gwT[i0] = gw[(long)e * H_ + k];
  }
  if (i0 < PADCAP) { tok_list[i0] = 0; wt_list[i0] = 0.f; }
  if (i0 < E_) { counts[i0] = 0; cursor[i0] = 0; }
  if (i0 < 2) qheads[i0] = 0;

  long stride = (long)gridDim.x * blockDim.x;
  for (long i = i0; i < W4_TOT; i += stride) {
    const float* s; long off; long dofs;
    if (i < W4_WG)       { s = wg;  off = i;            dofs = off * 4; }
    else if (i < W4_WU)  { s = wu;  off = i - W4_WG;    dofs = OFF_BU + off * 4; }
    else if (i < W4_WD)  { s = wd;  off = i - W4_WU;    dofs = OFF_BD + off * 4; }
    else if (i < W4_SHG) { s = shg; off = i - W4_WD;    dofs = OFF_BSHG + off * 4; }
    else if (i < W4_SHU) { s = shu; off = i - W4_SHG;   dofs = OFF_BSHU + off * 4; }
    else                 { s = shd; off = i - W4_SHU;   dofs = OFF_BSHD + off * 4; }
    float4 v = ((const float4*)s)[off];
    ushort4 o;
    o.x = f2bf(v.x); o.y = f2bf(v.y); o.z = f2bf(v.z); o.w = f2bf(v.w);
    *(ushort4*)(wbf + dofs) = o;
  }
}

// ---------------- logits: split-K partials + hs->bf16 -----------------------
__global__ __launch_bounds__(256) void logits_kernel(
    const float* __restrict__ h, const float* __restrict__ gwT,
    float* __restrict__ lpart,   // [8][T][E]
    u16* __restrict__ hbf, int T) {
  __shared__ float shh[64][128];
  __shared__ float shw[128][E_];
  const int tid = threadIdx.x;
  const int t0 = blockIdx.x * 64;
  const int k0 = blockIdx.y * 128;
  #pragma unroll
  for (int i = 0; i < 8; ++i) {
    int c = tid + 256 * i;
    int row = c >> 5, col = c & 31;
    float4 v = *(const float4*)(h + (size_t)(t0 + row) * H_ + k0 + col * 4);
    *(float4*)(&shh[row][col * 4]) = v;
    ushort4 o;
    o.x = f2bf(v.x); o.y = f2bf(v.y); o.z = f2bf(v.z); o.w = f2bf(v.w);
    *(ushort4*)(hbf + (size_t)(t0 + row) * H_ + k0 + col * 4) = o;
  }
  #pragma unroll
  for (int i = 0; i < 4; ++i) {
    int c = tid + 256 * i;
    int row = c >> 3, col = c & 7;
    *(float4*)(&shw[row][col * 4]) =
        *(const float4*)(gwT + (size_t)(k0 + row) * E_ + col * 4);
  }
  __syncthreads();
  const int e = tid & 31;
  const int tb = (tid >> 5) * 8;
  float acc[8] = {0.f, 0.f, 0.f, 0.f, 0.f, 0.f, 0.f, 0.f};
  #pragma unroll 4
  for (int k = 0; k < 128; ++k) {
    float wv = shw[k][e];
    #pragma unroll
    for (int j = 0; j < 8; ++j) acc[j] += shh[tb + j][k] * wv;
  }
  #pragma unroll
  for (int j = 0; j < 8; ++j)
    lpart[((size_t)blockIdx.y * T + (t0 + tb + j)) * E_ + e] = acc[j];
}

// ---------------- topk: wave-parallel (lane=expert, half-wave=token) --------
__global__ __launch_bounds__(256) void topk_kernel(
    const float* __restrict__ lpart, const float* __restrict__ gb,
    int* __restrict__ idx8, float* __restrict__ wt8, int* __restrict__ counts,
    int T) {
  const int tid = threadIdx.x;
  const int l = tid & 63, wid = tid >> 6;
  const int e = l & 31, half = l >> 5;
  const int t = blockIdx.x * 8 + wid * 2 + half;

  float lg = 0.f;
  #pragma unroll
  for (int s = 0; s < 8; ++s) lg += lpart[((size_t)s * T + t) * E_ + e];
  float score = 1.f / (1.f + __expf(-lg));
  float sc = score + gb[e];

  float x1 = __shfl_xor(sc, 1);
  float x2 = __shfl_xor(sc, 2);
  float x3 = __shfl_xor(sc, 3);
  float hi1 = fmaxf(sc, x1), lo1 = fminf(sc, x1);
  float hi2 = fmaxf(x2, x3), lo2 = fminf(x2, x3);
  float m1 = fmaxf(hi1, hi2);
  float m2 = (hi1 >= hi2) ? fmaxf(lo1, hi2) : fmaxf(lo2, hi1);
  float gs = m1 + m2;

  float ga[8];
  #pragma unroll
  for (int g = 0; g < 8; ++g) ga[g] = __shfl(gs, (half << 5) + g * 4);
  unsigned gm = 0;
  #pragma unroll
  for (int r = 0; r < 4; ++r) {
    float bv = -1e30f; int bi = 0;
    #pragma unroll
    for (int g = 0; g < 8; ++g)
      if (!((gm >> g) & 1u) && ga[g] > bv) { bv = ga[g]; bi = g; }
    gm |= 1u << bi;
  }
  float msk = ((gm >> (e >> 2)) & 1u) ? sc : 0.f;

  float wsum = 0.f, myw = 0.f;
  int myi = 0;
  #pragma unroll
  for (int r = 0; r < 8; ++r) {
    float av = msk; int ai = e;
    #pragma unroll
    for (int m = 16; m; m >>= 1) {
      float ov = __shfl_xor(av, m);
      int oi = __shfl_xor(ai, m);
      if (ov > av || (ov == av && oi < ai)) { av = ov; ai = oi; }
    }
    float wscore = __shfl(score, (half << 5) + ai);
    wsum += wscore;
    if (e == r) { myi = ai; myw = wscore; }
    if (e == ai) msk = 0.f;
  }
  float inv = SCALE_ / (wsum + 1e-20f);
  if (e < 8) {
    idx8[(size_t)t * 8 + e] = myi;
    wt8[(size_t)t * 8 + e] = myw * inv;
    atomicAdd(&counts[myi], 1);
  }
}

// ---------------- fill (inline padded scan) ----------------
__global__ void fill_kernel(const int* __restrict__ idx8, const float* __restrict__ wt8,
                            const int* __restrict__ counts, int* __restrict__ cursor,
                            int* __restrict__ tok_list, float* __restrict__ wt_list,
                            int* __restrict__ pair_pos, int npair) {
  int i = blockIdx.x * blockDim.x + threadIdx.x;
  if (i >= npair) return;
  int e = idx8[i];
  int offz = 0;
  for (int k = 0; k < E_; ++k) {
    if (k == e) break;
    offz += ((counts[k] + 127) >> 7) << 7;
  }
  int p = atomicAdd(&cursor[e], 1);
  int slot = offz + p;
  tok_list[slot] = i >> 3;
  wt_list[slot] = wt8[i];
  pair_pos[i] = slot;
}

// ---------------- phase 1: persistent dual GEMM, 128tok x 64col -------------
// BK=32, 2-buffer, stage-before-compute + single syncthreads. LDS 33KB ->
// 4 blk/CU (16 waves/CU) with launch_bounds(256,4).
__global__ __launch_bounds__(256, 4) void p1_kernel(
    const u16* __restrict__ hbf,
    const u16* __restrict__ wbf,
    const int* __restrict__ counts,
    const int* __restrict__ tok_list, const float* __restrict__ wt_list,
    int* __restrict__ qheads,
    u16* __restrict__ gu,          // [PADCAP][512]
    u16* __restrict__ gu_sh,       // [T][1024]
    int T) {
  __shared__ u16 lsA[2][128 * 32];
  __shared__ u16 lsB0[2][64 * 32];
  __shared__ u16 lsB1[2][64 * 32];
  __shared__ int s_tok[128];
  __shared__ float s_wt[128];
  __shared__ int s_off[E_], s_ntt[E_];
  __shared__ int s_tot, s_tile;

  const int tid = threadIdx.x;
  if (tid == 0) {
    int run = 0, tot = 0;
    for (int e = 0; e < E_; ++e) {
      s_off[e] = run;
      int nt = (counts[e] + 127) >> 7;
      s_ntt[e] = nt;
      run += nt << 7;
      tot += nt * 8;                 // 8 nb (64-col) per tt
    }
    s_tot = tot + (T / 128) * 16;    // shared: 16 tt x 16 nb
  }

  const int w = tid >> 6, l = tid & 63;
  const int wr = w >> 1, wc = w & 1;
  const int lr = l & 15, lh = l >> 4;
  const int rdblk = (lh ^ ((lr >> 1) & 3)) << 3;

  const int rA0 = tid >> 2,          cb0 = tid & 3, sc0 = cb0 ^ ((rA0 >> 1) & 3);
  const int rA1 = (tid + 256) >> 2,  sc1 = cb0 ^ ((rA1 >> 1) & 3);

  for (;;) {
    __syncthreads();
    if (tid == 0) s_tile = atomicAdd(&qheads[0], 1);
    __syncthreads();
    int q = s_tile;
    if (q >= s_tot) break;

    int z = 0, rem = q;
    for (; z < E_; ++z) { int t = s_ntt[z] * 8; if (rem < t) break; rem -= t; }
    const bool sh_e = (z == E_);
    int tt, nb;
    if (sh_e) { nb = rem >> 4; tt = rem & 15; }
    else      { int nt = s_ntt[z]; nb = rem / nt; tt = rem - nb * nt; }
    const int off = sh_e ? 0 : s_off[z];

    if (tid < 128) {
      if (sh_e) { s_tok[tid] = tt * 128 + tid; s_wt[tid] = 1.0f; }
      else {
        int slot = off + tt * 128 + tid;
        s_tok[tid] = tok_list[slot];
        s_wt[tid] = wt_list[slot];
      }
    }
    __syncthreads();

    const u16* Bg = sh_e ? (wbf + OFF_BSHG + (size_t)(nb * 64) * H_)
                         : (wbf + ((size_t)z * I_ + nb * 64) * H_);
    const u16* Bu = sh_e ? (wbf + OFF_BSHU + (size_t)(nb * 64) * H_)
                         : (wbf + OFF_BU + ((size_t)z * I_ + nb * 64) * H_);
    const u16* A0p = hbf + (size_t)s_tok[rA0] * H_ + sc0 * 8;
    const u16* A1p = hbf + (size_t)s_tok[rA1] * H_ + sc1 * 8;
    const u16* Bgp = Bg + (size_t)rA0 * H_ + sc0 * 8;
    const u16* Bup = Bu + (size_t)rA0 * H_ + sc0 * 8;

    f32x4_t acc0[4][2], acc1[4][2];
    #pragma unroll
    for (int m = 0; m < 4; ++m)
      #pragma unroll
      for (int n = 0; n < 2; ++n) {
        acc0[m][n] = (f32x4_t){0.f, 0.f, 0.f, 0.f};
        acc1[m][n] = (f32x4_t){0.f, 0.f, 0.f, 0.f};
      }

    auto stage = [&](int b, int ks) {   // 4 loads / thread
      int k0 = ks * 32;
      load_lds16(A0p + k0, (char*)&lsA[b][0] + tid * 16);
      load_lds16(A1p + k0, (char*)&lsA[b][0] + (tid + 256) * 16);
      load_lds16(Bgp + k0, (char*)&lsB0[b][0] + tid * 16);
      load_lds16(Bup + k0, (char*)&lsB1[b][0] + tid * 16);
    };
    auto compute = [&](int b) {
      bf16x8_t af[4], b0f[2], b1f[2];
      #pragma unroll
      for (int m = 0; m < 4; ++m)
        af[m] = *(const bf16x8_t*)(&lsA[b][0] + (wr * 64 + m * 16 + lr) * 32 + rdblk);
      #pragma unroll
      for (int n = 0; n < 2; ++n) {
        b0f[n] = *(const bf16x8_t*)(&lsB0[b][0] + (wc * 32 + n * 16 + lr) * 32 + rdblk);
        b1f[n] = *(const bf16x8_t*)(&lsB1[b][0] + (wc * 32 + n * 16 + lr) * 32 + rdblk);
      }
      #pragma unroll
      for (int m = 0; m < 4; ++m)
        #pragma unroll
        for (int n = 0; n < 2; ++n) {
          acc0[m][n] = __builtin_amdgcn_mfma_f32_16x16x32_bf16(af[m], b0f[n], acc0[m][n], 0, 0, 0);
          acc1[m][n] = __builtin_amdgcn_mfma_f32_16x16x32_bf16(af[m], b1f[n], acc1[m][n], 0, 0, 0);
        }
    };

    stage(0, 0);
    __syncthreads();
    int cur = 0;
    #pragma unroll 1
    for (int s = 0; s < 32; ++s) {
      if (s < 31) stage(cur ^ 1, s + 1);
      compute(cur);
      __syncthreads();
      cur ^= 1;
    }

    const int ldo = sh_e ? (I_ * NSH_) : I_;
    u16* outp = sh_e ? (gu_sh + (size_t)(tt * 128) * ldo + nb * 64)
                     : (gu + (size_t)(off + tt * 128) * ldo + nb * 64);
    #pragma unroll
    for (int m = 0; m < 4; ++m) {
      #pragma unroll
      for (int n = 0; n < 2; ++n) {
        int col = wc * 32 + n * 16 + lr;
        #pragma unroll
        for (int j = 0; j < 4; ++j) {
          int trow = wr * 64 + m * 16 + lh * 4 + j;
          float gv = acc0[m][n][j], uv = acc1[m][n][j];
          float sv = gv / (1.f + __expf(-gv));
          outp[(size_t)trow * ldo + col] = f2bf(sv * uv * s_wt[trow]);
        }
      }
    }
  }
}

// ---------------- phase 2: persistent GEMM (down), 128x128, BK=32 -----------
// 2-buffer, stage-before-compute + single syncthreads. LDS 32KB -> 4 blk/CU.
__global__ __launch_bounds__(256, 4) void p2_kernel(
    const u16* __restrict__ gu, const u16* __restrict__ gu_sh,
    const u16* __restrict__ wbf,
    const int* __restrict__ counts,
    int* __restrict__ qheads,
    u16* __restrict__ part,        // [PADCAP][H]
    u16* __restrict__ part_sh,     // [T][H]
    int T) {
  __shared__ u16 lsA[2][128 * 32];
  __shared__ u16 lsB[2][128 * 32];
  __shared__ int s_off[E_], s_ntt[E_];
  __shared__ int s_tot, s_tile;

  const int tid = threadIdx.x;
  if (tid == 0) {
    int run = 0, tot = 0;
    for (int e = 0; e < E_; ++e) {
      s_off[e] = run;
      int nt = (counts[e] + 127) >> 7;
      s_ntt[e] = nt;
      run += nt << 7;
      tot += nt * 8;
    }
    s_tot = tot + (T / 128) * 8;
  }

  const int w = tid >> 6, l = tid & 63;
  const int wr = w >> 1, wc = w & 1;
  const int lr = l & 15, lh = l >> 4;
  const int rdblk = (lh ^ ((lr >> 1) & 3)) << 3;

  const int c0 = tid, c1 = tid + 256;
  const int row0 = c0 >> 2, cb0 = c0 & 3, scb0 = cb0 ^ ((row0 >> 1) & 3);
  const int row1 = c1 >> 2, cb1 = c1 & 3, scb1 = cb1 ^ ((row1 >> 1) & 3);

  for (;;) {
    __syncthreads();
    if (tid == 0) s_tile = atomicAdd(&qheads[1], 1);
    __syncthreads();
    int q = s_tile;
    if (q >= s_tot) break;

    int z = 0, rem = q;
    for (; z < E_; ++z) { int t = s_ntt[z] * 8; if (rem < t) break; rem -= t; }
    const bool sh_e = (z == E_);
    int tt = rem >> 3, nb = rem & 7;

    const int K = sh_e ? (I_ * NSH_) : I_;
    const int NT = K / 32;
    const u16* Ab = sh_e ? (gu_sh + (size_t)(tt * 128) * K)
                         : (gu + (size_t)(s_off[z] + tt * 128) * K);
    const u16* Bb = sh_e ? (wbf + OFF_BSHD + (size_t)(nb * 128) * K)
                         : (wbf + OFF_BD + (size_t)z * H_ * I_ + (size_t)(nb * 128) * K);
    u16* outp = sh_e ? (part_sh + (size_t)(tt * 128) * H_ + nb * 128)
                     : (part + (size_t)(s_off[z] + tt * 128) * H_ + nb * 128);

    f32x4_t acc[4][4];
    #pragma unroll
    for (int m = 0; m < 4; ++m)
      #pragma unroll
      for (int n = 0; n < 4; ++n) acc[m][n] = (f32x4_t){0.f, 0.f, 0.f, 0.f};

    auto stage = [&](int b, int ks) {
      int k0 = ks * 32;
      load_lds16(Ab + (size_t)row0 * K + k0 + scb0 * 8, (char*)&lsA[b][0] + c0 * 16);
      load_lds16(Ab + (size_t)row1 * K + k0 + scb1 * 8, (char*)&lsA[b][0] + c1 * 16);
      load_lds16(Bb + (size_t)row0 * K + k0 + scb0 * 8, (char*)&lsB[b][0] + c0 * 16);
      load_lds16(Bb + (size_t)row1 * K + k0 + scb1 * 8, (char*)&lsB[b][0] + c1 * 16);
    };
    auto compute = [&](int b) {
      bf16x8_t af[4], bf[4];
      #pragma unroll
      for (int m = 0; m < 4; ++m)
        af[m] = *(const bf16x8_t*)(&lsA[b][0] + (wr * 64 + m * 16 + lr) * 32 + rdblk);
      #pragma unroll
      for (int n = 0; n < 4; ++n)
        bf[n] = *(const bf16x8_t*)(&lsB[b][0] + (wc * 64 + n * 16 + lr) * 32 + rdblk);
      #pragma unroll
      for (int m = 0; m < 4; ++m)
        #pragma unroll
        for (int n = 0; n < 4; ++n)
          acc[m][n] = __builtin_amdgcn_mfma_f32_16x16x32_bf16(af[m], bf[n], acc[m][n], 0, 0, 0);
    };

    stage(0, 0);
    __syncthreads();
    int cur = 0;
    #pragma unroll 1
    for (int s = 0; s < NT; ++s) {
      if (s < NT - 1) stage(cur ^ 1, s + 1);
      compute(cur);
      __syncthreads();
      cur ^= 1;
    }

    #pragma unroll
    for (int m = 0; m < 4; ++m) {
      #pragma unroll
      for (int n = 0; n < 4; ++n) {
        int col = wc * 64 + n * 16 + lr;
        #pragma unroll
        for (int j = 0; j < 4; ++j) {
          int trow = wr * 64 + m * 16 + lh * 4 + j;
          outp[(size_t)trow * H_ + col] = f2bf(acc[m][n][j]);
        }
      }
    }
  }
}

// ---------------- combine ----------------
__global__ void combine_kernel(const u16* __restrict__ part, const u16* __restrict__ part_sh,
                               const int* __restrict__ pair_pos, float* __restrict__ out) {
  int t = blockIdx.x;
  int h = threadIdx.x * 4;
  int pp[8];
  #pragma unroll
  for (int s = 0; s < 8; ++s) pp[s] = pair_pos[(long)t * 8 + s];
  ushort4 v = *(const ushort4*)(part_sh + (size_t)t * H_ + h);
  float a0 = bf2f(v.x), a1 = bf2f(v.y), a2 = bf2f(v.z), a3 = bf2f(v.w);
  #pragma unroll
  for (int s = 0; s < 8; ++s) {
    ushort4 u = *(const ushort4*)(part + (size_t)pp[s] * H_ + h);
    a0 += bf2f(u.x); a1 += bf2f(u.y); a2 += bf2f(u.z); a3 += bf2f(u.w);
  }
  float4 o = {a0, a1, a2, a3};
  *(float4*)(out + (size_t)t * H_ + h) = o;
}

extern "C" void kernel_launch(void* const* d_in, const int* in_sizes, int n_in,
                              void* d_out, int out_size, void* d_ws, size_t ws_size,
                              hipStream_t stream) {
  const float* hs  = (const float*)d_in[0];
  const float* gw  = (const float*)d_in[1];
  const float* gb  = (const float*)d_in[2];
  const float* wg  = (const float*)d_in[3];
  const float* wu  = (const float*)d_in[4];
  const float* wd  = (const float*)d_in[5];
  const float* shg = (const float*)d_in[6];
  const float* shu = (const float*)d_in[7];
  const float* shd = (const float*)d_in[8];
  float* out = (float*)d_out;

  const int T = in_sizes[0] / H_;  // 2048

  char* ws = (char*)d_ws;
  size_t off = 0;
  auto alloc = [&](size_t bytes) {
    char* p = ws + off;
    off += (bytes + 255) & ~(size_t)255;
    return p;
  };
  int*   counts   = (int*)alloc(E_ * 4);
  int*   cursor   = (int*)alloc(E_ * 4);
  int*   qheads   = (int*)alloc(2 * 4);
  int*   idx8     = (int*)alloc((size_t)T * 8 * 4);
  float* wt8      = (float*)alloc((size_t)T * 8 * 4);
  int*   pair_pos = (int*)alloc((size_t)T * 8 * 4);
  int*   tok_list = (int*)alloc(PADCAP * 4);
  float* wt_list  = (float*)alloc(PADCAP * 4);
  float* gwT      = (float*)alloc((size_t)H_ * E_ * 4);
  float* lpart    = (float*)alloc((size_t)8 * T * E_ * 4);
  u16* hbf     = (u16*)alloc((size_t)T * H_ * 2);
  u16* wbf     = (u16*)alloc((size_t)WBF_TOT * 2);
  u16* gu      = (u16*)alloc((size_t)PADCAP * I_ * 2);
  u16* gu_sh   = (u16*)alloc((size_t)T * I_ * NSH_ * 2);
  u16* part    = (u16*)alloc((size_t)PADCAP * H_ * 2);
  u16* part_sh = (u16*)alloc((size_t)T * H_ * 2);
  if (off > ws_size) return;

  hipLaunchKernelGGL(prep_kernel, dim3(4096), dim3(256), 0, stream,
                     gw, gwT, counts, cursor, qheads, tok_list, wt_list,
                     wg, wu, wd, shg, shu, shd, wbf);

  hipLaunchKernelGGL(logits_kernel, dim3(T / 64, 8), dim3(256), 0, stream,
                     hs, gwT, lpart, hbf, T);

  hipLaunchKernelGGL(topk_kernel, dim3(T / 8), dim3(256), 0, stream,
                     lpart, gb, idx8, wt8, counts, T);

  hipLaunchKernelGGL(fill_kernel, dim3((T * 8 + 255) / 256), dim3(256), 0, stream,
                     idx8, wt8, counts, cursor, tok_list, wt_list, pair_pos, T * 8);

  hipLaunchKernelGGL(p1_kernel, dim3(1024), dim3(256), 0, stream,
                     hbf, wbf, counts, tok_list, wt_list, qheads, gu, gu_sh, T);

  hipLaunchKernelGGL(p2_kernel, dim3(1024), dim3(256), 0, stream,
                     gu, gu_sh, wbf, counts, qheads, part, part_sh, T);

  hipLaunchKernelGGL(combine_kernel, dim3(T), dim3(256), 0, stream,
                     part, part_sh, pair_pos, out);
}

// Round 19
// 267.953 us; speedup vs baseline: 1.1174x; 1.1174x over previous
//
#include <hip/hip_runtime.h>
#include <hip/hip_bf16.h>
#include <cstdint>

#define E_ 32
#define H_ 1024
#define I_ 512
#define G_ 8
#define NSH_ 2
#define SCALE_ 2.5f
#define NROUTED (E_ * I_)            // 16384
#define PADCAP (16384 + E_ * 128)    // 20480, pad-to-128

typedef unsigned short u16;
using bf16x8_t = __attribute__((ext_vector_type(8))) __bf16;
using f32x4_t  = __attribute__((ext_vector_type(4))) float;

__device__ __forceinline__ u16 f2bf(float x) {
  union { float f; uint32_t u; } v; v.f = x;
  uint32_t u = v.u;
  uint32_t r = (u + 0x7fffu + ((u >> 16) & 1u)) >> 16;
  return (u16)r;
}
__device__ __forceinline__ float bf2f(u16 x) {
  union { uint32_t u; float f; } v; v.u = ((uint32_t)x) << 16; return v.f;
}

__device__ __forceinline__ void load_lds16(const void* g, void* l) {
  __builtin_amdgcn_global_load_lds(
      (const __attribute__((address_space(1))) unsigned int*)g,
      (__attribute__((address_space(3))) unsigned int*)l,
      16, 0, 0);
}

// u16-element offsets inside wbf: [bg | bu | bd | bshg | bshu | bshd]
#define OFF_BU   16777216L
#define OFF_BD   33554432L
#define OFF_BSHG 50331648L
#define OFF_BSHU 51380224L
#define OFF_BSHD 52428800L
#define WBF_TOT  53477376L

#define W4_WG  4194304L
#define W4_WU  8388608L
#define W4_WD  12582912L
#define W4_SHG 12845056L
#define W4_SHU 13107200L
#define W4_TOT 13369344L

// ---------------- prep: init + gw transpose + all-weight f32->bf16 ----------
__global__ void prep_kernel(const float* __restrict__ gw, float* __restrict__ gwT,
                            int* __restrict__ counts, int* __restrict__ cursor,
                            int* __restrict__ qheads,
                            int* __restrict__ tok_list, float* __restrict__ wt_list,
                            const float* __restrict__ wg, const float* __restrict__ wu,
                            const float* __restrict__ wd, const float* __restrict__ shg,
                            const float* __restrict__ shu, const float* __restrict__ shd,
                            u16* __restrict__ wbf) {
  long i0 = (long)blockIdx.x * blockDim.x + threadIdx.x;
  if (i0 < H_ * E_) {
    int k = (int)(i0 >> 5), e = (int)(i0 & 31);
    gwT[i0] = gw[(long)e * H_ + k];
  }
  if (i0 < PADCAP) { tok_list[i0] = 0; wt_list[i0] = 0.f; }
  if (i0 < E_) { counts[i0] = 0; cursor[i0] = 0; }
  if (i0 < 2) qheads[i0] = 0;

  long stride = (long)gridDim.x * blockDim.x;
  for (long i = i0; i < W4_TOT; i += stride) {
    const float* s; long off; long dofs;
    if (i < W4_WG)       { s = wg;  off = i;            dofs = off * 4; }
    else if (i < W4_WU)  { s = wu;  off = i - W4_WG;    dofs = OFF_BU + off * 4; }
    else if (i < W4_WD)  { s = wd;  off = i - W4_WU;    dofs = OFF_BD + off * 4; }
    else if (i < W4_SHG) { s = shg; off = i - W4_WD;    dofs = OFF_BSHG + off * 4; }
    else if (i < W4_SHU) { s = shu; off = i - W4_SHG;   dofs = OFF_BSHU + off * 4; }
    else                 { s = shd; off = i - W4_SHU;   dofs = OFF_BSHD + off * 4; }
    float4 v = ((const float4*)s)[off];
    ushort4 o;
    o.x = f2bf(v.x); o.y = f2bf(v.y); o.z = f2bf(v.z); o.w = f2bf(v.w);
    *(ushort4*)(wbf + dofs) = o;
  }
}

// ---------------- logits: split-K partials + hs->bf16 -----------------------
__global__ __launch_bounds__(256) void logits_kernel(
    const float* __restrict__ h, const float* __restrict__ gwT,
    float* __restrict__ lpart,   // [8][T][E]
    u16* __restrict__ hbf, int T) {
  __shared__ float shh[64][128];
  __shared__ float shw[128][E_];
  const int tid = threadIdx.x;
  const int t0 = blockIdx.x * 64;
  const int k0 = blockIdx.y * 128;
  #pragma unroll
  for (int i = 0; i < 8; ++i) {
    int c = tid + 256 * i;
    int row = c >> 5, col = c & 31;
    float4 v = *(const float4*)(h + (size_t)(t0 + row) * H_ + k0 + col * 4);
    *(float4*)(&shh[row][col * 4]) = v;
    ushort4 o;
    o.x = f2bf(v.x); o.y = f2bf(v.y); o.z = f2bf(v.z); o.w = f2bf(v.w);
    *(ushort4*)(hbf + (size_t)(t0 + row) * H_ + k0 + col * 4) = o;
  }
  #pragma unroll
  for (int i = 0; i < 4; ++i) {
    int c = tid + 256 * i;
    int row = c >> 3, col = c & 7;
    *(float4*)(&shw[row][col * 4]) =
        *(const float4*)(gwT + (size_t)(k0 + row) * E_ + col * 4);
  }
  __syncthreads();
  const int e = tid & 31;
  const int tb = (tid >> 5) * 8;
  float acc[8] = {0.f, 0.f, 0.f, 0.f, 0.f, 0.f, 0.f, 0.f};
  #pragma unroll 4
  for (int k = 0; k < 128; ++k) {
    float wv = shw[k][e];
    #pragma unroll
    for (int j = 0; j < 8; ++j) acc[j] += shh[tb + j][k] * wv;
  }
  #pragma unroll
  for (int j = 0; j < 8; ++j)
    lpart[((size_t)blockIdx.y * T + (t0 + tb + j)) * E_ + e] = acc[j];
}

// ---------------- topk: wave-parallel (lane=expert, half-wave=token) --------
__global__ __launch_bounds__(256) void topk_kernel(
    const float* __restrict__ lpart, const float* __restrict__ gb,
    int* __restrict__ idx8, float* __restrict__ wt8, int* __restrict__ counts,
    int T) {
  const int tid = threadIdx.x;
  const int l = tid & 63, wid = tid >> 6;
  const int e = l & 31, half = l >> 5;
  const int t = blockIdx.x * 8 + wid * 2 + half;

  float lg = 0.f;
  #pragma unroll
  for (int s = 0; s < 8; ++s) lg += lpart[((size_t)s * T + t) * E_ + e];
  float score = 1.f / (1.f + __expf(-lg));
  float sc = score + gb[e];

  float x1 = __shfl_xor(sc, 1);
  float x2 = __shfl_xor(sc, 2);
  float x3 = __shfl_xor(sc, 3);
  float hi1 = fmaxf(sc, x1), lo1 = fminf(sc, x1);
  float hi2 = fmaxf(x2, x3), lo2 = fminf(x2, x3);
  float m1 = fmaxf(hi1, hi2);
  float m2 = (hi1 >= hi2) ? fmaxf(lo1, hi2) : fmaxf(lo2, hi1);
  float gs = m1 + m2;

  float ga[8];
  #pragma unroll
  for (int g = 0; g < 8; ++g) ga[g] = __shfl(gs, (half << 5) + g * 4);
  unsigned gm = 0;
  #pragma unroll
  for (int r = 0; r < 4; ++r) {
    float bv = -1e30f; int bi = 0;
    #pragma unroll
    for (int g = 0; g < 8; ++g)
      if (!((gm >> g) & 1u) && ga[g] > bv) { bv = ga[g]; bi = g; }
    gm |= 1u << bi;
  }
  float msk = ((gm >> (e >> 2)) & 1u) ? sc : 0.f;

  float wsum = 0.f, myw = 0.f;
  int myi = 0;
  #pragma unroll
  for (int r = 0; r < 8; ++r) {
    float av = msk; int ai = e;
    #pragma unroll
    for (int m = 16; m; m >>= 1) {
      float ov = __shfl_xor(av, m);
      int oi = __shfl_xor(ai, m);
      if (ov > av || (ov == av && oi < ai)) { av = ov; ai = oi; }
    }
    float wscore = __shfl(score, (half << 5) + ai);
    wsum += wscore;
    if (e == r) { myi = ai; myw = wscore; }
    if (e == ai) msk = 0.f;
  }
  float inv = SCALE_ / (wsum + 1e-20f);
  if (e < 8) {
    idx8[(size_t)t * 8 + e] = myi;
    wt8[(size_t)t * 8 + e] = myw * inv;
    atomicAdd(&counts[myi], 1);
  }
}

// ---------------- fill (inline padded scan) ----------------
__global__ void fill_kernel(const int* __restrict__ idx8, const float* __restrict__ wt8,
                            const int* __restrict__ counts, int* __restrict__ cursor,
                            int* __restrict__ tok_list, float* __restrict__ wt_list,
                            int* __restrict__ pair_pos, int npair) {
  int i = blockIdx.x * blockDim.x + threadIdx.x;
  if (i >= npair) return;
  int e = idx8[i];
  int offz = 0;
  for (int k = 0; k < E_; ++k) {
    if (k == e) break;
    offz += ((counts[k] + 127) >> 7) << 7;
  }
  int p = atomicAdd(&cursor[e], 1);
  int slot = offz + p;
  tok_list[slot] = i >> 3;
  wt_list[slot] = wt8[i];
  pair_pos[i] = slot;
}

// ---------------- phase 1: persistent dual GEMM, 128tok x 64col -------------
// BK=32, 3-buffer depth-2 counted-vmcnt pipeline, acc=64 -> 3 blk/CU.
__global__ __launch_bounds__(256, 3) void p1_kernel(
    const u16* __restrict__ hbf,
    const u16* __restrict__ wbf,
    const int* __restrict__ counts,
    const int* __restrict__ tok_list, const float* __restrict__ wt_list,
    int* __restrict__ qheads,
    u16* __restrict__ gu,          // [PADCAP][512]
    u16* __restrict__ gu_sh,       // [T][1024]
    int T) {
  __shared__ u16 lsA[3][128 * 32];
  __shared__ u16 lsB0[3][64 * 32];
  __shared__ u16 lsB1[3][64 * 32];
  __shared__ int s_tok[128];
  __shared__ float s_wt[128];
  __shared__ int s_off[E_], s_ntt[E_];
  __shared__ int s_tot, s_tile;

  const int tid = threadIdx.x;
  if (tid == 0) {
    int run = 0, tot = 0;
    for (int e = 0; e < E_; ++e) {
      s_off[e] = run;
      int nt = (counts[e] + 127) >> 7;
      s_ntt[e] = nt;
      run += nt << 7;
      tot += nt * 8;                 // 8 nb (64-col) per tt
    }
    s_tot = tot + (T / 128) * 16;    // shared: 16 tt x 16 nb
  }

  const int w = tid >> 6, l = tid & 63;
  const int wr = w >> 1, wc = w & 1;
  const int lr = l & 15, lh = l >> 4;
  const int rdblk = (lh ^ ((lr >> 1) & 3)) << 3;

  const int rA0 = tid >> 2,          cb0 = tid & 3, sc0 = cb0 ^ ((rA0 >> 1) & 3);
  const int rA1 = (tid + 256) >> 2,  sc1 = cb0 ^ ((rA1 >> 1) & 3);

  for (;;) {
    __syncthreads();
    if (tid == 0) s_tile = atomicAdd(&qheads[0], 1);
    __syncthreads();
    int q = s_tile;
    if (q >= s_tot) break;

    int z = 0, rem = q;
    for (; z < E_; ++z) { int t = s_ntt[z] * 8; if (rem < t) break; rem -= t; }
    const bool sh_e = (z == E_);
    int tt, nb;
    if (sh_e) { nb = rem >> 4; tt = rem & 15; }
    else      { int nt = s_ntt[z]; nb = rem / nt; tt = rem - nb * nt; }
    const int off = sh_e ? 0 : s_off[z];

    if (tid < 128) {
      if (sh_e) { s_tok[tid] = tt * 128 + tid; s_wt[tid] = 1.0f; }
      else {
        int slot = off + tt * 128 + tid;
        s_tok[tid] = tok_list[slot];
        s_wt[tid] = wt_list[slot];
      }
    }
    __syncthreads();

    const u16* Bg = sh_e ? (wbf + OFF_BSHG + (size_t)(nb * 64) * H_)
                         : (wbf + ((size_t)z * I_ + nb * 64) * H_);
    const u16* Bu = sh_e ? (wbf + OFF_BSHU + (size_t)(nb * 64) * H_)
                         : (wbf + OFF_BU + ((size_t)z * I_ + nb * 64) * H_);
    const u16* A0p = hbf + (size_t)s_tok[rA0] * H_ + sc0 * 8;
    const u16* A1p = hbf + (size_t)s_tok[rA1] * H_ + sc1 * 8;
    const u16* Bgp = Bg + (size_t)rA0 * H_ + sc0 * 8;
    const u16* Bup = Bu + (size_t)rA0 * H_ + sc0 * 8;

    f32x4_t acc0[4][2], acc1[4][2];
    #pragma unroll
    for (int m = 0; m < 4; ++m)
      #pragma unroll
      for (int n = 0; n < 2; ++n) {
        acc0[m][n] = (f32x4_t){0.f, 0.f, 0.f, 0.f};
        acc1[m][n] = (f32x4_t){0.f, 0.f, 0.f, 0.f};
      }

    auto stage = [&](int b, int ks) {   // 4 loads / thread
      int k0 = ks * 32;
      load_lds16(A0p + k0, (char*)&lsA[b][0] + tid * 16);
      load_lds16(A1p + k0, (char*)&lsA[b][0] + (tid + 256) * 16);
      load_lds16(Bgp + k0, (char*)&lsB0[b][0] + tid * 16);
      load_lds16(Bup + k0, (char*)&lsB1[b][0] + tid * 16);
    };
    auto compute = [&](int b) {
      bf16x8_t af[4], b0f[2], b1f[2];
      #pragma unroll
      for (int m = 0; m < 4; ++m)
        af[m] = *(const bf16x8_t*)(&lsA[b][0] + (wr * 64 + m * 16 + lr) * 32 + rdblk);
      #pragma unroll
      for (int n = 0; n < 2; ++n) {
        b0f[n] = *(const bf16x8_t*)(&lsB0[b][0] + (wc * 32 + n * 16 + lr) * 32 + rdblk);
        b1f[n] = *(const bf16x8_t*)(&lsB1[b][0] + (wc * 32 + n * 16 + lr) * 32 + rdblk);
      }
      #pragma unroll
      for (int m = 0; m < 4; ++m)
        #pragma unroll
        for (int n = 0; n < 2; ++n) {
          acc0[m][n] = __builtin_amdgcn_mfma_f32_16x16x32_bf16(af[m], b0f[n], acc0[m][n], 0, 0, 0);
          acc1[m][n] = __builtin_amdgcn_mfma_f32_16x16x32_bf16(af[m], b1f[n], acc1[m][n], 0, 0, 0);
        }
    };

    stage(0, 0);
    stage(1, 1);
    int b0 = 0, b1 = 1, b2 = 2;
    #pragma unroll 1
    for (int s = 0; s < 31; ++s) {
      asm volatile("s_waitcnt vmcnt(4)" ::: "memory");
      __builtin_amdgcn_s_barrier();
      compute(b0);
      if (s < 30) stage(b2, s + 2);
      int tb = b0; b0 = b1; b1 = b2; b2 = tb;
    }
    asm volatile("s_waitcnt vmcnt(0)" ::: "memory");
    __builtin_amdgcn_s_barrier();
    compute(b0);

    const int ldo = sh_e ? (I_ * NSH_) : I_;
    u16* outp = sh_e ? (gu_sh + (size_t)(tt * 128) * ldo + nb * 64)
                     : (gu + (size_t)(off + tt * 128) * ldo + nb * 64);
    #pragma unroll
    for (int m = 0; m < 4; ++m) {
      #pragma unroll
      for (int n = 0; n < 2; ++n) {
        int col = wc * 32 + n * 16 + lr;
        #pragma unroll
        for (int j = 0; j < 4; ++j) {
          int trow = wr * 64 + m * 16 + lh * 4 + j;
          float gv = acc0[m][n][j], uv = acc1[m][n][j];
          float sv = gv / (1.f + __expf(-gv));
          outp[(size_t)trow * ldo + col] = f2bf(sv * uv * s_wt[trow]);
        }
      }
    }
  }
}

// ---------------- phase 2: persistent GEMM (down), 128x128, BK=32 -----------
// 3-buffer counted vmcnt(4), nb-innermost queue, direct epilogue.
__global__ __launch_bounds__(256, 3) void p2_kernel(
    const u16* __restrict__ gu, const u16* __restrict__ gu_sh,
    const u16* __restrict__ wbf,
    const int* __restrict__ counts,
    int* __restrict__ qheads,
    u16* __restrict__ part,        // [PADCAP][H]
    u16* __restrict__ part_sh,     // [T][H]
    int T) {
  __shared__ u16 lsA[3][128 * 32];
  __shared__ u16 lsB[3][128 * 32];
  __shared__ int s_off[E_], s_ntt[E_];
  __shared__ int s_tot, s_tile;

  const int tid = threadIdx.x;
  if (tid == 0) {
    int run = 0, tot = 0;
    for (int e = 0; e < E_; ++e) {
      s_off[e] = run;
      int nt = (counts[e] + 127) >> 7;
      s_ntt[e] = nt;
      run += nt << 7;
      tot += nt * 8;
    }
    s_tot = tot + (T / 128) * 8;
  }

  const int w = tid >> 6, l = tid & 63;
  const int wr = w >> 1, wc = w & 1;
  const int lr = l & 15, lh = l >> 4;
  const int rdblk = (lh ^ ((lr >> 1) & 3)) << 3;

  const int c0 = tid, c1 = tid + 256;
  const int row0 = c0 >> 2, cb0 = c0 & 3, scb0 = cb0 ^ ((row0 >> 1) & 3);
  const int row1 = c1 >> 2, cb1 = c1 & 3, scb1 = cb1 ^ ((row1 >> 1) & 3);

  for (;;) {
    __syncthreads();
    if (tid == 0) s_tile = atomicAdd(&qheads[1], 1);
    __syncthreads();
    int q = s_tile;
    if (q >= s_tot) break;

    int z = 0, rem = q;
    for (; z < E_; ++z) { int t = s_ntt[z] * 8; if (rem < t) break; rem -= t; }
    const bool sh_e = (z == E_);
    int tt = rem >> 3, nb = rem & 7;

    const int K = sh_e ? (I_ * NSH_) : I_;
    const int NT = K / 32;
    const u16* Ab = sh_e ? (gu_sh + (size_t)(tt * 128) * K)
                         : (gu + (size_t)(s_off[z] + tt * 128) * K);
    const u16* Bb = sh_e ? (wbf + OFF_BSHD + (size_t)(nb * 128) * K)
                         : (wbf + OFF_BD + (size_t)z * H_ * I_ + (size_t)(nb * 128) * K);
    u16* outp = sh_e ? (part_sh + (size_t)(tt * 128) * H_ + nb * 128)
                     : (part + (size_t)(s_off[z] + tt * 128) * H_ + nb * 128);

    f32x4_t acc[4][4];
    #pragma unroll
    for (int m = 0; m < 4; ++m)
      #pragma unroll
      for (int n = 0; n < 4; ++n) acc[m][n] = (f32x4_t){0.f, 0.f, 0.f, 0.f};

    auto stage = [&](int b, int ks) {
      int k0 = ks * 32;
      load_lds16(Ab + (size_t)row0 * K + k0 + scb0 * 8, (char*)&lsA[b][0] + c0 * 16);
      load_lds16(Ab + (size_t)row1 * K + k0 + scb1 * 8, (char*)&lsA[b][0] + c1 * 16);
      load_lds16(Bb + (size_t)row0 * K + k0 + scb0 * 8, (char*)&lsB[b][0] + c0 * 16);
      load_lds16(Bb + (size_t)row1 * K + k0 + scb1 * 8, (char*)&lsB[b][0] + c1 * 16);
    };
    auto compute = [&](int b) {
      bf16x8_t af[4], bf[4];
      #pragma unroll
      for (int m = 0; m < 4; ++m)
        af[m] = *(const bf16x8_t*)(&lsA[b][0] + (wr * 64 + m * 16 + lr) * 32 + rdblk);
      #pragma unroll
      for (int n = 0; n < 4; ++n)
        bf[n] = *(const bf16x8_t*)(&lsB[b][0] + (wc * 64 + n * 16 + lr) * 32 + rdblk);
      #pragma unroll
      for (int m = 0; m < 4; ++m)
        #pragma unroll
        for (int n = 0; n < 4; ++n)
          acc[m][n] = __builtin_amdgcn_mfma_f32_16x16x32_bf16(af[m], bf[n], acc[m][n], 0, 0, 0);
    };

    stage(0, 0);
    stage(1, 1);
    int b0 = 0, b1 = 1, b2 = 2;
    #pragma unroll 1
    for (int s = 0; s < NT - 1; ++s) {
      asm volatile("s_waitcnt vmcnt(4)" ::: "memory");
      __builtin_amdgcn_s_barrier();
      compute(b0);
      if (s + 2 < NT) stage(b2, s + 2);
      int tb = b0; b0 = b1; b1 = b2; b2 = tb;
    }
    asm volatile("s_waitcnt vmcnt(0)" ::: "memory");
    __builtin_amdgcn_s_barrier();
    compute(b0);

    #pragma unroll
    for (int m = 0; m < 4; ++m) {
      #pragma unroll
      for (int n = 0; n < 4; ++n) {
        int col = wc * 64 + n * 16 + lr;
        #pragma unroll
        for (int j = 0; j < 4; ++j) {
          int trow = wr * 64 + m * 16 + lh * 4 + j;
          outp[(size_t)trow * H_ + col] = f2bf(acc[m][n][j]);
        }
      }
    }
  }
}

// ---------------- combine ----------------
__global__ void combine_kernel(const u16* __restrict__ part, const u16* __restrict__ part_sh,
                               const int* __restrict__ pair_pos, float* __restrict__ out) {
  int t = blockIdx.x;
  int h = threadIdx.x * 4;
  int pp[8];
  #pragma unroll
  for (int s = 0; s < 8; ++s) pp[s] = pair_pos[(long)t * 8 + s];
  ushort4 v = *(const ushort4*)(part_sh + (size_t)t * H_ + h);
  float a0 = bf2f(v.x), a1 = bf2f(v.y), a2 = bf2f(v.z), a3 = bf2f(v.w);
  #pragma unroll
  for (int s = 0; s < 8; ++s) {
    ushort4 u = *(const ushort4*)(part + (size_t)pp[s] * H_ + h);
    a0 += bf2f(u.x); a1 += bf2f(u.y); a2 += bf2f(u.z); a3 += bf2f(u.w);
  }
  float4 o = {a0, a1, a2, a3};
  *(float4*)(out + (size_t)t * H_ + h) = o;
}

extern "C" void kernel_launch(void* const* d_in, const int* in_sizes, int n_in,
                              void* d_out, int out_size, void* d_ws, size_t ws_size,
                              hipStream_t stream) {
  const float* hs  = (const float*)d_in[0];
  const float* gw  = (const float*)d_in[1];
  const float* gb  = (const float*)d_in[2];
  const float* wg  = (const float*)d_in[3];
  const float* wu  = (const float*)d_in[4];
  const float* wd  = (const float*)d_in[5];
  const float* shg = (const float*)d_in[6];
  const float* shu = (const float*)d_in[7];
  const float* shd = (const float*)d_in[8];
  float* out = (float*)d_out;

  const int T = in_sizes[0] / H_;  // 2048

  char* ws = (char*)d_ws;
  size_t off = 0;
  auto alloc = [&](size_t bytes) {
    char* p = ws + off;
    off += (bytes + 255) & ~(size_t)255;
    return p;
  };
  int*   counts   = (int*)alloc(E_ * 4);
  int*   cursor   = (int*)alloc(E_ * 4);
  int*   qheads   = (int*)alloc(2 * 4);
  int*   idx8     = (int*)alloc((size_t)T * 8 * 4);
  float* wt8      = (float*)alloc((size_t)T * 8 * 4);
  int*   pair_pos = (int*)alloc((size_t)T * 8 * 4);
  int*   tok_list = (int*)alloc(PADCAP * 4);
  float* wt_list  = (float*)alloc(PADCAP * 4);
  float* gwT      = (float*)alloc((size_t)H_ * E_ * 4);
  float* lpart    = (float*)alloc((size_t)8 * T * E_ * 4);
  u16* hbf     = (u16*)alloc((size_t)T * H_ * 2);
  u16* wbf     = (u16*)alloc((size_t)WBF_TOT * 2);
  u16* gu      = (u16*)alloc((size_t)PADCAP * I_ * 2);
  u16* gu_sh   = (u16*)alloc((size_t)T * I_ * NSH_ * 2);
  u16* part    = (u16*)alloc((size_t)PADCAP * H_ * 2);
  u16* part_sh = (u16*)alloc((size_t)T * H_ * 2);
  if (off > ws_size) return;

  hipLaunchKernelGGL(prep_kernel, dim3(4096), dim3(256), 0, stream,
                     gw, gwT, counts, cursor, qheads, tok_list, wt_list,
                     wg, wu, wd, shg, shu, shd, wbf);

  hipLaunchKernelGGL(logits_kernel, dim3(T / 64, 8), dim3(256), 0, stream,
                     hs, gwT, lpart, hbf, T);

  hipLaunchKernelGGL(topk_kernel, dim3(T / 8), dim3(256), 0, stream,
                     lpart, gb, idx8, wt8, counts, T);

  hipLaunchKernelGGL(fill_kernel, dim3((T * 8 + 255) / 256), dim3(256), 0, stream,
                     idx8, wt8, counts, cursor, tok_list, wt_list, pair_pos, T * 8);

  hipLaunchKernelGGL(p1_kernel, dim3(768), dim3(256), 0, stream,
                     hbf, wbf, counts, tok_list, wt_list, qheads, gu, gu_sh, T);

  hipLaunchKernelGGL(p2_kernel, dim3(768), dim3(256), 0, stream,
                     gu, gu_sh, wbf, counts, qheads, part, part_sh, T);

  hipLaunchKernelGGL(combine_kernel, dim3(T), dim3(256), 0, stream,
                     part, part_sh, pair_pos, out);
}

// Round 20
// 266.889 us; speedup vs baseline: 1.1218x; 1.0040x over previous
//
#include <hip/hip_runtime.h>
#include <hip/hip_bf16.h>
#include <cstdint>

#define E_ 32
#define H_ 1024
#define I_ 512
#define G_ 8
#define NSH_ 2
#define SCALE_ 2.5f
#define NROUTED (E_ * I_)            // 16384
#define PADCAP (16384 + E_ * 128)    // 20480, pad-to-128

typedef unsigned short u16;
using bf16x8_t = __attribute__((ext_vector_type(8))) __bf16;
using f32x4_t  = __attribute__((ext_vector_type(4))) float;

__device__ __forceinline__ u16 f2bf(float x) {
  union { float f; uint32_t u; } v; v.f = x;
  uint32_t u = v.u;
  uint32_t r = (u + 0x7fffu + ((u >> 16) & 1u)) >> 16;
  return (u16)r;
}
__device__ __forceinline__ float bf2f(u16 x) {
  union { uint32_t u; float f; } v; v.u = ((uint32_t)x) << 16; return v.f;
}

__device__ __forceinline__ void load_lds16(const void* g, void* l) {
  __builtin_amdgcn_global_load_lds(
      (const __attribute__((address_space(1))) unsigned int*)g,
      (__attribute__((address_space(3))) unsigned int*)l,
      16, 0, 0);
}

// u16-element offsets inside wbf: [bg | bu | bd | bshg | bshu | bshd]
#define OFF_BU   16777216L
#define OFF_BD   33554432L
#define OFF_BSHG 50331648L
#define OFF_BSHU 51380224L
#define OFF_BSHD 52428800L
#define WBF_TOT  53477376L

#define W4_WG  4194304L
#define W4_WU  8388608L
#define W4_WD  12582912L
#define W4_SHG 12845056L
#define W4_SHU 13107200L
#define W4_TOT 13369344L

// ---------------- prep: init + gw transpose + all-weight f32->bf16 ----------
__global__ void prep_kernel(const float* __restrict__ gw, float* __restrict__ gwT,
                            int* __restrict__ counts, int* __restrict__ cursor,
                            int* __restrict__ qheads,
                            int* __restrict__ tok_list, float* __restrict__ wt_list,
                            const float* __restrict__ wg, const float* __restrict__ wu,
                            const float* __restrict__ wd, const float* __restrict__ shg,
                            const float* __restrict__ shu, const float* __restrict__ shd,
                            u16* __restrict__ wbf) {
  long i0 = (long)blockIdx.x * blockDim.x + threadIdx.x;
  if (i0 < H_ * E_) {
    int k = (int)(i0 >> 5), e = (int)(i0 & 31);
    gwT[i0] = gw[(long)e * H_ + k];
  }
  if (i0 < PADCAP) { tok_list[i0] = 0; wt_list[i0] = 0.f; }
  if (i0 < E_) { counts[i0] = 0; cursor[i0] = 0; }
  if (i0 < 2) qheads[i0] = 0;

  long stride = (long)gridDim.x * blockDim.x;
  for (long i = i0; i < W4_TOT; i += stride) {
    const float* s; long off; long dofs;
    if (i < W4_WG)       { s = wg;  off = i;            dofs = off * 4; }
    else if (i < W4_WU)  { s = wu;  off = i - W4_WG;    dofs = OFF_BU + off * 4; }
    else if (i < W4_WD)  { s = wd;  off = i - W4_WU;    dofs = OFF_BD + off * 4; }
    else if (i < W4_SHG) { s = shg; off = i - W4_WD;    dofs = OFF_BSHG + off * 4; }
    else if (i < W4_SHU) { s = shu; off = i - W4_SHG;   dofs = OFF_BSHU + off * 4; }
    else                 { s = shd; off = i - W4_SHU;   dofs = OFF_BSHD + off * 4; }
    float4 v = ((const float4*)s)[off];
    ushort4 o;
    o.x = f2bf(v.x); o.y = f2bf(v.y); o.z = f2bf(v.z); o.w = f2bf(v.w);
    *(ushort4*)(wbf + dofs) = o;
  }
}

// ---------------- logits: split-K partials + hs->bf16 -----------------------
__global__ __launch_bounds__(256) void logits_kernel(
    const float* __restrict__ h, const float* __restrict__ gwT,
    float* __restrict__ lpart,   // [8][T][E]
    u16* __restrict__ hbf, int T) {
  __shared__ float shh[64][128];
  __shared__ float shw[128][E_];
  const int tid = threadIdx.x;
  const int t0 = blockIdx.x * 64;
  const int k0 = blockIdx.y * 128;
  #pragma unroll
  for (int i = 0; i < 8; ++i) {
    int c = tid + 256 * i;
    int row = c >> 5, col = c & 31;
    float4 v = *(const float4*)(h + (size_t)(t0 + row) * H_ + k0 + col * 4);
    *(float4*)(&shh[row][col * 4]) = v;
    ushort4 o;
    o.x = f2bf(v.x); o.y = f2bf(v.y); o.z = f2bf(v.z); o.w = f2bf(v.w);
    *(ushort4*)(hbf + (size_t)(t0 + row) * H_ + k0 + col * 4) = o;
  }
  #pragma unroll
  for (int i = 0; i < 4; ++i) {
    int c = tid + 256 * i;
    int row = c >> 3, col = c & 7;
    *(float4*)(&shw[row][col * 4]) =
        *(const float4*)(gwT + (size_t)(k0 + row) * E_ + col * 4);
  }
  __syncthreads();
  const int e = tid & 31;
  const int tb = (tid >> 5) * 8;
  float acc[8] = {0.f, 0.f, 0.f, 0.f, 0.f, 0.f, 0.f, 0.f};
  #pragma unroll 4
  for (int k = 0; k < 128; ++k) {
    float wv = shw[k][e];
    #pragma unroll
    for (int j = 0; j < 8; ++j) acc[j] += shh[tb + j][k] * wv;
  }
  #pragma unroll
  for (int j = 0; j < 8; ++j)
    lpart[((size_t)blockIdx.y * T + (t0 + tb + j)) * E_ + e] = acc[j];
}

// ---------------- topk: wave-parallel (lane=expert, half-wave=token) --------
__global__ __launch_bounds__(256) void topk_kernel(
    const float* __restrict__ lpart, const float* __restrict__ gb,
    int* __restrict__ idx8, float* __restrict__ wt8, int* __restrict__ counts,
    int T) {
  const int tid = threadIdx.x;
  const int l = tid & 63, wid = tid >> 6;
  const int e = l & 31, half = l >> 5;
  const int t = blockIdx.x * 8 + wid * 2 + half;

  float lg = 0.f;
  #pragma unroll
  for (int s = 0; s < 8; ++s) lg += lpart[((size_t)s * T + t) * E_ + e];
  float score = 1.f / (1.f + __expf(-lg));
  float sc = score + gb[e];

  float x1 = __shfl_xor(sc, 1);
  float x2 = __shfl_xor(sc, 2);
  float x3 = __shfl_xor(sc, 3);
  float hi1 = fmaxf(sc, x1), lo1 = fminf(sc, x1);
  float hi2 = fmaxf(x2, x3), lo2 = fminf(x2, x3);
  float m1 = fmaxf(hi1, hi2);
  float m2 = (hi1 >= hi2) ? fmaxf(lo1, hi2) : fmaxf(lo2, hi1);
  float gs = m1 + m2;

  float ga[8];
  #pragma unroll
  for (int g = 0; g < 8; ++g) ga[g] = __shfl(gs, (half << 5) + g * 4);
  unsigned gm = 0;
  #pragma unroll
  for (int r = 0; r < 4; ++r) {
    float bv = -1e30f; int bi = 0;
    #pragma unroll
    for (int g = 0; g < 8; ++g)
      if (!((gm >> g) & 1u) && ga[g] > bv) { bv = ga[g]; bi = g; }
    gm |= 1u << bi;
  }
  float msk = ((gm >> (e >> 2)) & 1u) ? sc : 0.f;

  float wsum = 0.f, myw = 0.f;
  int myi = 0;
  #pragma unroll
  for (int r = 0; r < 8; ++r) {
    float av = msk; int ai = e;
    #pragma unroll
    for (int m = 16; m; m >>= 1) {
      float ov = __shfl_xor(av, m);
      int oi = __shfl_xor(ai, m);
      if (ov > av || (ov == av && oi < ai)) { av = ov; ai = oi; }
    }
    float wscore = __shfl(score, (half << 5) + ai);
    wsum += wscore;
    if (e == r) { myi = ai; myw = wscore; }
    if (e == ai) msk = 0.f;
  }
  float inv = SCALE_ / (wsum + 1e-20f);
  if (e < 8) {
    idx8[(size_t)t * 8 + e] = myi;
    wt8[(size_t)t * 8 + e] = myw * inv;
    atomicAdd(&counts[myi], 1);
  }
}

// ---------------- fill (inline padded scan) ----------------
__global__ void fill_kernel(const int* __restrict__ idx8, const float* __restrict__ wt8,
                            const int* __restrict__ counts, int* __restrict__ cursor,
                            int* __restrict__ tok_list, float* __restrict__ wt_list,
                            int* __restrict__ pair_pos, int npair) {
  int i = blockIdx.x * blockDim.x + threadIdx.x;
  if (i >= npair) return;
  int e = idx8[i];
  int offz = 0;
  for (int k = 0; k < E_; ++k) {
    if (k == e) break;
    offz += ((counts[k] + 127) >> 7) << 7;
  }
  int p = atomicAdd(&cursor[e], 1);
  int slot = offz + p;
  tok_list[slot] = i >> 3;
  wt_list[slot] = wt8[i];
  pair_pos[i] = slot;
}

// ---------------- phase 1: persistent dual GEMM, 128tok x 64col -------------
// BK=32, 3-buffer depth-2 counted-vmcnt pipeline, acc=64 -> 3 blk/CU.
__global__ __launch_bounds__(256, 3) void p1_kernel(
    const u16* __restrict__ hbf,
    const u16* __restrict__ wbf,
    const int* __restrict__ counts,
    const int* __restrict__ tok_list, const float* __restrict__ wt_list,
    int* __restrict__ qheads,
    u16* __restrict__ gu,          // [PADCAP][512]
    u16* __restrict__ gu_sh,       // [T][1024]
    int T) {
  __shared__ u16 lsA[3][128 * 32];
  __shared__ u16 lsB0[3][64 * 32];
  __shared__ u16 lsB1[3][64 * 32];
  __shared__ int s_tok[128];
  __shared__ float s_wt[128];
  __shared__ int s_off[E_], s_ntt[E_];
  __shared__ int s_tot, s_tile;

  const int tid = threadIdx.x;
  if (tid == 0) {
    int run = 0, tot = 0;
    for (int e = 0; e < E_; ++e) {
      s_off[e] = run;
      int nt = (counts[e] + 127) >> 7;
      s_ntt[e] = nt;
      run += nt << 7;
      tot += nt * 8;                 // 8 nb (64-col) per tt
    }
    s_tot = tot + (T / 128) * 16;    // shared: 16 tt x 16 nb
  }

  const int w = tid >> 6, l = tid & 63;
  const int wr = w >> 1, wc = w & 1;
  const int lr = l & 15, lh = l >> 4;
  const int rdblk = (lh ^ ((lr >> 1) & 3)) << 3;

  const int rA0 = tid >> 2,          cb0 = tid & 3, sc0 = cb0 ^ ((rA0 >> 1) & 3);
  const int rA1 = (tid + 256) >> 2,  sc1 = cb0 ^ ((rA1 >> 1) & 3);

  for (;;) {
    __syncthreads();
    if (tid == 0) s_tile = atomicAdd(&qheads[0], 1);
    __syncthreads();
    int q = s_tile;
    if (q >= s_tot) break;

    int z = 0, rem = q;
    for (; z < E_; ++z) { int t = s_ntt[z] * 8; if (rem < t) break; rem -= t; }
    const bool sh_e = (z == E_);
    int tt, nb;
    if (sh_e) { nb = rem >> 4; tt = rem & 15; }
    else      { int nt = s_ntt[z]; nb = rem / nt; tt = rem - nb * nt; }
    const int off = sh_e ? 0 : s_off[z];

    if (tid < 128) {
      if (sh_e) { s_tok[tid] = tt * 128 + tid; s_wt[tid] = 1.0f; }
      else {
        int slot = off + tt * 128 + tid;
        s_tok[tid] = tok_list[slot];
        s_wt[tid] = wt_list[slot];
      }
    }
    __syncthreads();

    const u16* Bg = sh_e ? (wbf + OFF_BSHG + (size_t)(nb * 64) * H_)
                         : (wbf + ((size_t)z * I_ + nb * 64) * H_);
    const u16* Bu = sh_e ? (wbf + OFF_BSHU + (size_t)(nb * 64) * H_)
                         : (wbf + OFF_BU + ((size_t)z * I_ + nb * 64) * H_);
    const u16* A0p = hbf + (size_t)s_tok[rA0] * H_ + sc0 * 8;
    const u16* A1p = hbf + (size_t)s_tok[rA1] * H_ + sc1 * 8;
    const u16* Bgp = Bg + (size_t)rA0 * H_ + sc0 * 8;
    const u16* Bup = Bu + (size_t)rA0 * H_ + sc0 * 8;

    f32x4_t acc0[4][2], acc1[4][2];
    #pragma unroll
    for (int m = 0; m < 4; ++m)
      #pragma unroll
      for (int n = 0; n < 2; ++n) {
        acc0[m][n] = (f32x4_t){0.f, 0.f, 0.f, 0.f};
        acc1[m][n] = (f32x4_t){0.f, 0.f, 0.f, 0.f};
      }

    auto stage = [&](int b, int ks) {   // 4 loads / thread
      int k0 = ks * 32;
      load_lds16(A0p + k0, (char*)&lsA[b][0] + tid * 16);
      load_lds16(A1p + k0, (char*)&lsA[b][0] + (tid + 256) * 16);
      load_lds16(Bgp + k0, (char*)&lsB0[b][0] + tid * 16);
      load_lds16(Bup + k0, (char*)&lsB1[b][0] + tid * 16);
    };
    auto compute = [&](int b) {
      bf16x8_t af[4], b0f[2], b1f[2];
      #pragma unroll
      for (int m = 0; m < 4; ++m)
        af[m] = *(const bf16x8_t*)(&lsA[b][0] + (wr * 64 + m * 16 + lr) * 32 + rdblk);
      #pragma unroll
      for (int n = 0; n < 2; ++n) {
        b0f[n] = *(const bf16x8_t*)(&lsB0[b][0] + (wc * 32 + n * 16 + lr) * 32 + rdblk);
        b1f[n] = *(const bf16x8_t*)(&lsB1[b][0] + (wc * 32 + n * 16 + lr) * 32 + rdblk);
      }
      #pragma unroll
      for (int m = 0; m < 4; ++m)
        #pragma unroll
        for (int n = 0; n < 2; ++n) {
          acc0[m][n] = __builtin_amdgcn_mfma_f32_16x16x32_bf16(af[m], b0f[n], acc0[m][n], 0, 0, 0);
          acc1[m][n] = __builtin_amdgcn_mfma_f32_16x16x32_bf16(af[m], b1f[n], acc1[m][n], 0, 0, 0);
        }
    };

    stage(0, 0);
    stage(1, 1);
    int b0 = 0, b1 = 1, b2 = 2;
    #pragma unroll 1
    for (int s = 0; s < 31; ++s) {
      asm volatile("s_waitcnt vmcnt(4)" ::: "memory");
      __builtin_amdgcn_s_barrier();
      compute(b0);
      if (s < 30) stage(b2, s + 2);
      int tb = b0; b0 = b1; b1 = b2; b2 = tb;
    }
    asm volatile("s_waitcnt vmcnt(0)" ::: "memory");
    __builtin_amdgcn_s_barrier();
    compute(b0);

    const int ldo = sh_e ? (I_ * NSH_) : I_;
    u16* outp = sh_e ? (gu_sh + (size_t)(tt * 128) * ldo + nb * 64)
                     : (gu + (size_t)(off + tt * 128) * ldo + nb * 64);
    #pragma unroll
    for (int m = 0; m < 4; ++m) {
      #pragma unroll
      for (int n = 0; n < 2; ++n) {
        int col = wc * 32 + n * 16 + lr;
        #pragma unroll
        for (int j = 0; j < 4; ++j) {
          int trow = wr * 64 + m * 16 + lh * 4 + j;
          float gv = acc0[m][n][j], uv = acc1[m][n][j];
          float sv = gv / (1.f + __expf(-gv));
          outp[(size_t)trow * ldo + col] = f2bf(sv * uv * s_wt[trow]);
        }
      }
    }
  }
}

// ---------------- phase 2: persistent GEMM (down), 128x128, BK=32 -----------
// 3-buffer counted vmcnt(4), nb-innermost queue, direct epilogue.
__global__ __launch_bounds__(256, 3) void p2_kernel(
    const u16* __restrict__ gu, const u16* __restrict__ gu_sh,
    const u16* __restrict__ wbf,
    const int* __restrict__ counts,
    int* __restrict__ qheads,
    u16* __restrict__ part,        // [PADCAP][H]
    u16* __restrict__ part_sh,     // [T][H]
    int T) {
  __shared__ u16 lsA[3][128 * 32];
  __shared__ u16 lsB[3][128 * 32];
  __shared__ int s_off[E_], s_ntt[E_];
  __shared__ int s_tot, s_tile;

  const int tid = threadIdx.x;
  if (tid == 0) {
    int run = 0, tot = 0;
    for (int e = 0; e < E_; ++e) {
      s_off[e] = run;
      int nt = (counts[e] + 127) >> 7;
      s_ntt[e] = nt;
      run += nt << 7;
      tot += nt * 8;
    }
    s_tot = tot + (T / 128) * 8;
  }

  const int w = tid >> 6, l = tid & 63;
  const int wr = w >> 1, wc = w & 1;
  const int lr = l & 15, lh = l >> 4;
  const int rdblk = (lh ^ ((lr >> 1) & 3)) << 3;

  const int c0 = tid, c1 = tid + 256;
  const int row0 = c0 >> 2, cb0 = c0 & 3, scb0 = cb0 ^ ((row0 >> 1) & 3);
  const int row1 = c1 >> 2, cb1 = c1 & 3, scb1 = cb1 ^ ((row1 >> 1) & 3);

  for (;;) {
    __syncthreads();
    if (tid == 0) s_tile = atomicAdd(&qheads[1], 1);
    __syncthreads();
    int q = s_tile;
    if (q >= s_tot) break;

    int z = 0, rem = q;
    for (; z < E_; ++z) { int t = s_ntt[z] * 8; if (rem < t) break; rem -= t; }
    const bool sh_e = (z == E_);
    int tt = rem >> 3, nb = rem & 7;

    const int K = sh_e ? (I_ * NSH_) : I_;
    const int NT = K / 32;
    const u16* Ab = sh_e ? (gu_sh + (size_t)(tt * 128) * K)
                         : (gu + (size_t)(s_off[z] + tt * 128) * K);
    const u16* Bb = sh_e ? (wbf + OFF_BSHD + (size_t)(nb * 128) * K)
                         : (wbf + OFF_BD + (size_t)z * H_ * I_ + (size_t)(nb * 128) * K);
    u16* outp = sh_e ? (part_sh + (size_t)(tt * 128) * H_ + nb * 128)
                     : (part + (size_t)(s_off[z] + tt * 128) * H_ + nb * 128);

    f32x4_t acc[4][4];
    #pragma unroll
    for (int m = 0; m < 4; ++m)
      #pragma unroll
      for (int n = 0; n < 4; ++n) acc[m][n] = (f32x4_t){0.f, 0.f, 0.f, 0.f};

    auto stage = [&](int b, int ks) {
      int k0 = ks * 32;
      load_lds16(Ab + (size_t)row0 * K + k0 + scb0 * 8, (char*)&lsA[b][0] + c0 * 16);
      load_lds16(Ab + (size_t)row1 * K + k0 + scb1 * 8, (char*)&lsA[b][0] + c1 * 16);
      load_lds16(Bb + (size_t)row0 * K + k0 + scb0 * 8, (char*)&lsB[b][0] + c0 * 16);
      load_lds16(Bb + (size_t)row1 * K + k0 + scb1 * 8, (char*)&lsB[b][0] + c1 * 16);
    };
    auto compute = [&](int b) {
      bf16x8_t af[4], bf[4];
      #pragma unroll
      for (int m = 0; m < 4; ++m)
        af[m] = *(const bf16x8_t*)(&lsA[b][0] + (wr * 64 + m * 16 + lr) * 32 + rdblk);
      #pragma unroll
      for (int n = 0; n < 4; ++n)
        bf[n] = *(const bf16x8_t*)(&lsB[b][0] + (wc * 64 + n * 16 + lr) * 32 + rdblk);
      #pragma unroll
      for (int m = 0; m < 4; ++m)
        #pragma unroll
        for (int n = 0; n < 4; ++n)
          acc[m][n] = __builtin_amdgcn_mfma_f32_16x16x32_bf16(af[m], bf[n], acc[m][n], 0, 0, 0);
    };

    stage(0, 0);
    stage(1, 1);
    int b0 = 0, b1 = 1, b2 = 2;
    #pragma unroll 1
    for (int s = 0; s < NT - 1; ++s) {
      asm volatile("s_waitcnt vmcnt(4)" ::: "memory");
      __builtin_amdgcn_s_barrier();
      compute(b0);
      if (s + 2 < NT) stage(b2, s + 2);
      int tb = b0; b0 = b1; b1 = b2; b2 = tb;
    }
    asm volatile("s_waitcnt vmcnt(0)" ::: "memory");
    __builtin_amdgcn_s_barrier();
    compute(b0);

    #pragma unroll
    for (int m = 0; m < 4; ++m) {
      #pragma unroll
      for (int n = 0; n < 4; ++n) {
        int col = wc * 64 + n * 16 + lr;
        #pragma unroll
        for (int j = 0; j < 4; ++j) {
          int trow = wr * 64 + m * 16 + lh * 4 + j;
          outp[(size_t)trow * H_ + col] = f2bf(acc[m][n][j]);
        }
      }
    }
  }
}

// ---------------- combine ----------------
__global__ void combine_kernel(const u16* __restrict__ part, const u16* __restrict__ part_sh,
                               const int* __restrict__ pair_pos, float* __restrict__ out) {
  int t = blockIdx.x;
  int h = threadIdx.x * 4;
  int pp[8];
  #pragma unroll
  for (int s = 0; s < 8; ++s) pp[s] = pair_pos[(long)t * 8 + s];
  ushort4 v = *(const ushort4*)(part_sh + (size_t)t * H_ + h);
  float a0 = bf2f(v.x), a1 = bf2f(v.y), a2 = bf2f(v.z), a3 = bf2f(v.w);
  #pragma unroll
  for (int s = 0; s < 8; ++s) {
    ushort4 u = *(const ushort4*)(part + (size_t)pp[s] * H_ + h);
    a0 += bf2f(u.x); a1 += bf2f(u.y); a2 += bf2f(u.z); a3 += bf2f(u.w);
  }
  float4 o = {a0, a1, a2, a3};
  *(float4*)(out + (size_t)t * H_ + h) = o;
}

extern "C" void kernel_launch(void* const* d_in, const int* in_sizes, int n_in,
                              void* d_out, int out_size, void* d_ws, size_t ws_size,
                              hipStream_t stream) {
  const float* hs  = (const float*)d_in[0];
  const float* gw  = (const float*)d_in[1];
  const float* gb  = (const float*)d_in[2];
  const float* wg  = (const float*)d_in[3];
  const float* wu  = (const float*)d_in[4];
  const float* wd  = (const float*)d_in[5];
  const float* shg = (const float*)d_in[6];
  const float* shu = (const float*)d_in[7];
  const float* shd = (const float*)d_in[8];
  float* out = (float*)d_out;

  const int T = in_sizes[0] / H_;  // 2048

  char* ws = (char*)d_ws;
  size_t off = 0;
  auto alloc = [&](size_t bytes) {
    char* p = ws + off;
    off += (bytes + 255) & ~(size_t)255;
    return p;
  };
  int*   counts   = (int*)alloc(E_ * 4);
  int*   cursor   = (int*)alloc(E_ * 4);
  int*   qheads   = (int*)alloc(2 * 4);
  int*   idx8     = (int*)alloc((size_t)T * 8 * 4);
  float* wt8      = (float*)alloc((size_t)T * 8 * 4);
  int*   pair_pos = (int*)alloc((size_t)T * 8 * 4);
  int*   tok_list = (int*)alloc(PADCAP * 4);
  float* wt_list  = (float*)alloc(PADCAP * 4);
  float* gwT      = (float*)alloc((size_t)H_ * E_ * 4);
  float* lpart    = (float*)alloc((size_t)8 * T * E_ * 4);
  u16* hbf     = (u16*)alloc((size_t)T * H_ * 2);
  u16* wbf     = (u16*)alloc((size_t)WBF_TOT * 2);
  u16* gu      = (u16*)alloc((size_t)PADCAP * I_ * 2);
  u16* gu_sh   = (u16*)alloc((size_t)T * I_ * NSH_ * 2);
  u16* part    = (u16*)alloc((size_t)PADCAP * H_ * 2);
  u16* part_sh = (u16*)alloc((size_t)T * H_ * 2);
  if (off > ws_size) return;

  hipLaunchKernelGGL(prep_kernel, dim3(4096), dim3(256), 0, stream,
                     gw, gwT, counts, cursor, qheads, tok_list, wt_list,
                     wg, wu, wd, shg, shu, shd, wbf);

  hipLaunchKernelGGL(logits_kernel, dim3(T / 64, 8), dim3(256), 0, stream,
                     hs, gwT, lpart, hbf, T);

  hipLaunchKernelGGL(topk_kernel, dim3(T / 8), dim3(256), 0, stream,
                     lpart, gb, idx8, wt8, counts, T);

  hipLaunchKernelGGL(fill_kernel, dim3((T * 8 + 255) / 256), dim3(256), 0, stream,
                     idx8, wt8, counts, cursor, tok_list, wt_list, pair_pos, T * 8);

  hipLaunchKernelGGL(p1_kernel, dim3(768), dim3(256), 0, stream,
                     hbf, wbf, counts, tok_list, wt_list, qheads, gu, gu_sh, T);

  hipLaunchKernelGGL(p2_kernel, dim3(768), dim3(256), 0, stream,
                     gu, gu_sh, wbf, counts, qheads, part, part_sh, T);

  hipLaunchKernelGGL(combine_kernel, dim3(T), dim3(256), 0, stream,
                     part, part_sh, pair_pos, out);
}